// Round 9
// baseline (109.716 us; speedup 1.0000x reference)
//
#include <hip/hip_runtime.h>
#include <math.h>

#define NDEG 64          // N
#define LDCB 67          // cBar/sBar row stride (N + 3)

#define MU_F   398600441800000.0f
#define AREF_F 6378136.3f

#define NSUB 8           // sub-waves per element group
#define EPW  64          // elements per wave (= wave size)
#define SGRP 72          // Cons4 groups per stream (max used = 72 for some j)
#define SF4  (SGRP * 4)  // float4 per stream = 288
#define NREC 9           // head records per j (8 columns + m=64 tail)

// ---------------------------------------------------------------------------
// Setup: grid 2 x 128.
// Block 0, thread h < 72: head record (j,k):
//   hrec[h*2+0] = (diag[m], sub[m+1]*diag[m+1], cB[m][m]|0, sB[m][m]|0)
//   hrec[h*2+1] = (cB[m+1][m]|0, sB[m+1][m]|0, 0, 0)
//   record k=8 is the m=64 diagonal tail (zeros unless j=0).
// Block 1, thread t < 64: column (j = t>>3, k = t&7) of the zigzag
// (m = j,15-j,16+j,31-j,32+j,47-j,48+j,63-j), writing its padded entries
// into stream j (each column padded to a multiple of 8 entries):
//   entry l: ( ntilde2, ghat*cBar[l][m], ghat*sBar[l][m], 0 )
//   ntilde2 = n2/(n1(l)*n1(l-1)); TELESCOPES to the rational
//     (l+m-1)(l-m-1)/((2l-1)(2l-3)) for l>=m+3; sqrt(1/(2m+3)) at l=m+2.
//   ghat_l = prod n1 = sqrt(G_l), G accumulated rationally in f64.
// O(column) work per thread: ~1 f64 sqrt per entry.
// ---------------------------------------------------------------------------
__global__ void pines_setup(const float* __restrict__ cBar,
                            const float* __restrict__ sBar,
                            float4* __restrict__ stream,   // 8*SF4 float4
                            float4* __restrict__ hrec) {   // 8*NREC*2 float4
    int t = threadIdx.x;
    if (blockIdx.x == 0) {
        if (t < 8 * NREC) {
            int j = t / NREC, k = t % NREC;
            int d1 = 15 - 2 * j, d2 = 1 + 2 * j;
            int m = j;
            for (int kk = 0; kk < k; ++kk) m += (kk & 1) ? d2 : d1;
            float4 a = make_float4(0.0f, 0.0f, 0.0f, 0.0f);
            float4 b = make_float4(0.0f, 0.0f, 0.0f, 0.0f);
            if (m <= NDEG) {
                double diag = 1.0;
                for (int l = 1; l <= m; ++l) {
                    double kp = (l == 1) ? 1.0 : 2.0;   // k[l-1]
                    diag *= sqrt((2.0 * l + 1.0) * 2.0 / (2.0 * l * kp));
                }
                double sd = 0.0;
                if (m < NDEG) {
                    double kprev = (m == 0) ? 1.0 : 2.0;              // k[m]
                    double f    = sqrt((2.0 * (m + 1) + 1.0) * 2.0 /
                                       (2.0 * (m + 1) * kprev));      // f(m+1)
                    double sub1 = sqrt((double)(m + 1) * kprev);      // sub[m+1]
                    sd = sub1 * diag * f;
                }
                float cmm = (m >= 1) ? cBar[m * LDCB + m] : 0.0f;
                float smm = (m >= 1) ? sBar[m * LDCB + m] : 0.0f;
                float cb1 = (m < NDEG) ? cBar[(m + 1) * LDCB + m] : 0.0f;
                float sb1 = (m < NDEG) ? sBar[(m + 1) * LDCB + m] : 0.0f;
                a = make_float4((float)diag, (float)sd, cmm, smm);
                b = make_float4(cb1, sb1, 0.0f, 0.0f);
            }
            hrec[t * 2]     = a;
            hrec[t * 2 + 1] = b;
        }
    } else {
        if (t < 64) {
            int j = t >> 3, k = t & 7;
            int d1 = 15 - 2 * j, d2 = 1 + 2 * j;
            int m = j, base = 0;
            for (int kk = 0; kk < k; ++kk) {
                int len = 63 - m;
                base += ((len + 7) >> 3) << 3;
                m += (kk & 1) ? d2 : d1;
            }
            int len  = 63 - m;
            int ecap = ((len + 7) >> 3) << 3;
            float4* __restrict__ dst = stream + j * SF4 + base;
            double G = 1.0;
            for (int i = 0; i < ecap; ++i) {
                float4 v = make_float4(0.0f, 0.0f, 0.0f, 0.0f);
                if (i < len) {
                    int l = m + 2 + i;
                    G *= (2.0 * l + 1.0) * (2.0 * l - 1.0) /
                         ((double)(l - m) * (l + m));
                    double g = sqrt(G);
                    double nt2 = (i == 0)
                        ? sqrt(1.0 / (2.0 * m + 3.0))
                        : ((double)(l + m - 1) * (l - m - 1)) /
                          ((double)(2 * l - 1) * (2 * l - 3));
                    v = make_float4((float)nt2,
                                    (float)(g * (double)cBar[l * LDCB + m]),
                                    (float)(g * (double)sBar[l * LDCB + m]),
                                    0.0f);
                }
                dst[i] = v;
            }
        }
    }
}

// ---------------------------------------------------------------------------
// Main kernel. Block = 512 = 8 waves; wave j, lanes = 64 elements. Each wave
// STAGES its private 4.6 KB stream into LDS (wave-private -> no barrier),
// then the inner loop reads it back as float4: ds_read_b128 returns are
// IN-ORDER and partially lgkmcnt-waitable, so the compiler software-
// pipelines them (impossible with s_load's OOO returns, which forced
// lgkmcnt(0) drains in R5-R8). Same-address LDS reads broadcast conflict-
// free. Heads stay SMEM, prefetched a column ahead. Recursion (fused):
//   q^ = fma(ur, q1, -rho2*(ntilde2*q0)); contrib via ctilde/stilde;
// mu/r factored into the final store. Pad entries (all-zero) are inert.
// ---------------------------------------------------------------------------
__global__ __launch_bounds__(512, 8) void pines_kernel(
        const float4* __restrict__ inputs,
        const float4* __restrict__ stream,
        const float4* __restrict__ hrec,
        float* __restrict__ out, int B) {
    __shared__ float4 sh[8 * SF4];         // 36,864 B staged streams
    __shared__ float part[NSUB][EPW];      //  2,048 B partial sums

    int t = threadIdx.x;
    int j = __builtin_amdgcn_readfirstlane(t >> 6);
    int e = t & (EPW - 1);
    int elem = blockIdx.x * EPW + e;
    int lelem = elem < B ? elem : (B - 1);

    // ---- stage this wave's stream into LDS (coalesced, wave-private) ----
    {
        const float4* __restrict__ src = stream + j * SF4;
        float4* __restrict__ dst = sh + j * SF4;
        #pragma unroll
        for (int i = 0; i < SF4 / EPW; ++i)          // 288/64 = 4.5 -> 4 + tail
            dst[e + i * EPW] = src[e + i * EPW];
        if (e < SF4 - (SF4 / EPW) * EPW + 0) {}      // (SF4 = 288 = 4*64 + 32)
        if (e < 32) dst[256 + e] = src[256 + e];
    }

    float4 in = inputs[lelem];
    float r = in.x, ss = in.y, tt = in.z, u = in.w;

    float rho   = AREF_F / r;
    float rho2  = rho * rho;
    float nrho2 = -rho2;
    float ur    = u * rho;

    int d1 = 15 - 2 * j;
    int d2 = 1 + 2 * j;

    auto cpow = [&](int e_, float& re_, float& im_) {
        float br = ss, bi = tt;
        re_ = 1.0f; im_ = 0.0f;
        int ee = e_;
        while (ee) {
            if (ee & 1) {
                float nr = re_ * br - im_ * bi;
                im_ = re_ * bi + im_ * br;
                re_ = nr;
            }
            float sr = br * br - bi * bi;
            bi = 2.0f * br * bi;
            br = sr;
            ee >>= 1;
        }
    };
    auto rpow = [&](int e_) {
        float b = rho, acc = 1.0f;
        int ee = e_;
        while (ee) {
            if (ee & 1) acc *= b;
            b *= b;
            ee >>= 1;
        }
        return acc;
    };

    float re, im;      cpow(j, re, im);
    float s1r, s1i;    cpow(d1, s1r, s1i);
    float s2r, s2i;    cpow(d2, s2r, s2i);
    float rstep1 = rpow(d1);
    float rstep2 = rpow(d2);
    float rho_m  = rpow(j);              // rho^m at m = j

    float sum = (j == 0) ? 1.0f : 0.0f;  // l = 0 term (times mu/r at end)

    const float4* __restrict__ hp = hrec + j * NREC * 2;
    const float4* __restrict__ wsh = sh + j * SF4;

    float4 h0 = hp[0];
    float4 h1 = hp[1];

    int m = j, gi = 0;
    #pragma unroll 1
    for (int k = 0; k < 8; ++k) {
        int sm = __builtin_amdgcn_readfirstlane(m);
        float4 h0n = hp[2 * k + 2];      // next column head (SMEM prefetch)
        float4 h1n = hp[2 * k + 3];

        float q0 = h0.x * rho_m;                       // q at l = m
        float sA = q0 * h0.z;
        float sB = q0 * h0.w;
        float q1 = (h0.y * u) * (rho_m * rho);         // q at l = m+1
        sA = fmaf(q1, h1.x, sA);
        sB = fmaf(q1, h1.y, sB);

        int ntr = __builtin_amdgcn_readfirstlane((63 - sm + 7) >> 3);
        #pragma unroll 1
        for (int tr = 0; tr < ntr; ++tr) {
            float4 c0 = wsh[gi + 0];                   // 8x ds_read_b128,
            float4 c1 = wsh[gi + 1];                   // in-order, compiler-
            float4 c2 = wsh[gi + 2];                   // pipelined lgkmcnt
            float4 c3 = wsh[gi + 3];
            float4 c4 = wsh[gi + 4];
            float4 c5 = wsh[gi + 5];
            float4 c6 = wsh[gi + 6];
            float4 c7 = wsh[gi + 7];
            gi += 8;
            #pragma unroll
            for (int q4 = 0; q4 < 8; ++q4) {
                float4 cc;
                switch (q4) {
                    case 0: cc = c0; break; case 1: cc = c1; break;
                    case 2: cc = c2; break; case 3: cc = c3; break;
                    case 4: cc = c4; break; case 5: cc = c5; break;
                    case 6: cc = c6; break; default: cc = c7; break;
                }
                float t3 = cc.x * q0;
                float t4 = nrho2 * t3;
                float q  = fmaf(ur, q1, t4);
                sA = fmaf(q, cc.y, sA);
                sB = fmaf(q, cc.z, sB);
                q0 = q1; q1 = q;
            }
        }
        sum = fmaf(re, sA, sum);
        sum = fmaf(im, sB, sum);

        // zigzag advance: even k -> +d1, odd k -> +d2
        if (k & 1) {
            float nr = re * s2r - im * s2i;
            im = re * s2i + im * s2r; re = nr;
            rho_m *= rstep2; m += d2;
        } else {
            float nr = re * s1r - im * s1i;
            im = re * s1i + im * s1r; re = nr;
            rho_m *= rstep1; m += d1;
        }
        h0 = h0n; h1 = h1n;
    }
    // m=64 diagonal tail: h0 == record 8 (zeros unless j==0) -> branchless
    {
        float q0 = h0.x * rho_m;
        sum = fmaf(re * q0, h0.z, sum);
        sum = fmaf(im * q0, h0.w, sum);
    }

    part[j][e] = sum;
    __syncthreads();
    if (j == 0) {
        float tot = 0.0f;
        #pragma unroll
        for (int q = 0; q < NSUB; ++q) tot += part[q][e];
        if (elem < B) out[elem] = -(MU_F / r) * tot;
    }
}

extern "C" void kernel_launch(void* const* d_in, const int* in_sizes, int n_in,
                              void* d_out, int out_size, void* d_ws, size_t ws_size,
                              hipStream_t stream_h) {
    const float* inputs = (const float*)d_in[0];   // (B, 4)
    const float* cBar   = (const float*)d_in[1];   // (67, 67)
    const float* sBar   = (const float*)d_in[2];   // (67, 67)
    float* out = (float*)d_out;
    int B = in_sizes[0] / 4;

    float4* strm = (float4*)d_ws;                  // 8*SF4 = 2304 float4
    float4* hrec = strm + 8 * SF4;                 // 8*NREC*2 = 144 float4

    hipLaunchKernelGGL(pines_setup, dim3(2), dim3(128), 0, stream_h,
                       cBar, sBar, strm, hrec);

    int blocks = (B + EPW - 1) / EPW;
    hipLaunchKernelGGL(pines_kernel, dim3(blocks), dim3(512), 0, stream_h,
                       (const float4*)inputs, strm, hrec, out, B);
}

// Round 10
// 93.177 us; speedup vs baseline: 1.1775x; 1.1775x over previous
//
#include <hip/hip_runtime.h>
#include <math.h>

#define NDEG 64          // N
#define LDCB 67          // cBar/sBar row stride (N + 3)

#define MU_F   398600441800000.0f
#define AREF_F 6378136.3f

#define NSUB 16          // sub-waves per element group (block = 1024)
#define EPW  64          // lanes per wave
#define SMAX 160         // float4 entries per stream (max used = 144)
#define NREC 5           // head records per j (4 columns + m=64 tail)

typedef float f2 __attribute__((ext_vector_type(2)));
__device__ __forceinline__ f2 make2(float x) { f2 v; v.x = x; v.y = x; return v; }

// 64 B group of 4 packed entries (ntilde2, ctilde, stilde, pad)
struct Cons4 { float4 v[4]; };

// zigzag columns of sub j: m = j, 31-j, 32+j, 63-j (lengths sum to 126 for all j)
__device__ __forceinline__ int zcol(int j, int k) {
    switch (k) { case 0: return j; case 1: return 31 - j;
                 case 2: return 32 + j; default: return 63 - j; }
}

// ---------------------------------------------------------------------------
// Setup: 1 block x 256.
// Threads 0..63: stream column (j = t>>2, c = t&3). Each column m packed as
// ceil(len/8)*8 entries (len = 63-m), entry l = m+2+i:
//   ( ntilde2, ghat*cBar[l][m], ghat*sBar[l][m], 0 )
//   ntilde2 = sqrt(1/(2m+3)) at l=m+2, else rational (l+m-1)(l-m-1)/((2l-1)(2l-3))
//   ghat = sqrt(G), G *= (2l+1)(2l-1)/((l-m)(l+m))   [same fused math as R9,
//   which validated absmax = 0.0]
// Threads 64..143: head record (j = h/5, k = h%5), m = zcol or 64-tail:
//   rec a = (diag[m], sub[m+1]*diag[m+1], cB[m][m]|0, sB[m][m]|0)
//   rec b = (cB[m+1][m]|0, sB[m+1][m]|0, 0, 0)
//   k=4: m=64 for j=0 (diag-only tail), zeros otherwise.
// ---------------------------------------------------------------------------
__global__ void pines_setup(const float* __restrict__ cBar,
                            const float* __restrict__ sBar,
                            float4* __restrict__ stream,   // NSUB*SMAX float4
                            float4* __restrict__ hrec) {   // NSUB*NREC*2 float4
    int t = threadIdx.x;
    if (t < 64) {
        int j = t >> 2, c = t & 3;
        int base = 0;
        for (int cc = 0; cc < c; ++cc) {
            int len = 63 - zcol(j, cc);
            base += ((len + 7) >> 3) << 3;
        }
        int m    = zcol(j, c);
        int len  = 63 - m;
        int ecap = ((len + 7) >> 3) << 3;
        float4* __restrict__ dst = stream + j * SMAX + base;
        double G = 1.0;
        for (int i = 0; i < ecap; ++i) {
            float4 v = make_float4(0.0f, 0.0f, 0.0f, 0.0f);
            if (i < len) {
                int l = m + 2 + i;
                G *= (2.0 * l + 1.0) * (2.0 * l - 1.0) /
                     ((double)(l - m) * (l + m));
                double g = sqrt(G);
                double nt2 = (i == 0)
                    ? sqrt(1.0 / (2.0 * m + 3.0))
                    : ((double)(l + m - 1) * (l - m - 1)) /
                      ((double)(2 * l - 1) * (2 * l - 3));
                v = make_float4((float)nt2,
                                (float)(g * (double)cBar[l * LDCB + m]),
                                (float)(g * (double)sBar[l * LDCB + m]),
                                0.0f);
            }
            dst[i] = v;
        }
    } else if (t < 64 + NSUB * NREC) {
        int h = t - 64;
        int j = h / NREC, k = h % NREC;
        int m = (k < 4) ? zcol(j, k) : ((j == 0) ? 64 : 99);
        float4 a = make_float4(0.0f, 0.0f, 0.0f, 0.0f);
        float4 b = make_float4(0.0f, 0.0f, 0.0f, 0.0f);
        if (m <= NDEG) {
            double diag = 1.0;
            for (int l = 1; l <= m; ++l) {
                double kp = (l == 1) ? 1.0 : 2.0;   // k[l-1]
                diag *= sqrt((2.0 * l + 1.0) * 2.0 / (2.0 * l * kp));
            }
            double sd = 0.0;
            if (m < NDEG) {
                double kprev = (m == 0) ? 1.0 : 2.0;              // k[m]
                double f    = sqrt((2.0 * (m + 1) + 1.0) * 2.0 /
                                   (2.0 * (m + 1) * kprev));      // f(m+1)
                double sub1 = sqrt((double)(m + 1) * kprev);      // sub[m+1]
                sd = sub1 * diag * f;
            }
            float cmm = (m >= 1) ? cBar[m * LDCB + m] : 0.0f;
            float smm = (m >= 1) ? sBar[m * LDCB + m] : 0.0f;
            float cb1 = (m < NDEG) ? cBar[(m + 1) * LDCB + m] : 0.0f;
            float sb1 = (m < NDEG) ? sBar[(m + 1) * LDCB + m] : 0.0f;
            a = make_float4((float)diag, (float)sd, cmm, smm);
            b = make_float4(cb1, sb1, 0.0f, 0.0f);
        }
        hrec[h * 2]     = a;
        hrec[h * 2 + 1] = b;
    }
}

// ---------------------------------------------------------------------------
// Main kernel. Block = 1024 = 16 waves; wave j = sub index; lane e handles
// TWO elements (base+e, base+64+e) with all state in float2 -> packed fp32
// (v_pk_fma_f32/v_pk_mul_f32): ~2x fewer issued VALU per element, and the
// wave-uniform SGPR coefficients broadcast into both halves. Columns of sub
// j: m = j, 31-j, 32+j, 63-j (lengths sum to 126 for every j). 2 blocks/CU
// (VGPR<=64 via launch_bounds) = 32 waves/CU. Coefficient loads are batched
// SMEM (2x s_load_dwordx16 per 8-entry trip, halved per element). Recursion
// (fused): q^ = ur*q1 - rho2*(nt2*q0); contrib via ctilde/stilde; mu/r at
// the final store. Pad entries (all-zero) inert.
// ---------------------------------------------------------------------------
__global__ __launch_bounds__(1024, 8) void pines_kernel(
        const float4* __restrict__ inputs,
        const float4* __restrict__ stream,
        const float4* __restrict__ hrec,
        float* __restrict__ out, int B) {
    __shared__ f2 part[NSUB][EPW];

    int t = threadIdx.x;
    int j = __builtin_amdgcn_readfirstlane(t >> 6);
    int e = t & (EPW - 1);
    int base = blockIdx.x * 128;
    int e0 = base + e;       if (e0 >= B) e0 = B - 1;
    int e1 = base + 64 + e;  if (e1 >= B) e1 = B - 1;

    float4 inA = inputs[e0];
    float4 inB = inputs[e1];
    f2 r, sv, tv, u;
    r.x = inA.x; r.y = inB.x;
    sv.x = inA.y; sv.y = inB.y;
    tv.x = inA.z; tv.y = inB.z;
    u.x = inA.w; u.y = inB.w;

    f2 rho   = AREF_F / r;
    f2 rho2  = rho * rho;
    f2 nrho2 = -rho2;
    f2 ur    = u * rho;

    int d1 = 31 - 2 * j;
    int d2 = 1 + 2 * j;

    auto cpow = [&](int e_, f2& re_, f2& im_) {
        f2 br = sv, bi = tv;
        re_ = make2(1.0f); im_ = make2(0.0f);
        int ee = e_;
        while (ee) {
            if (ee & 1) {
                f2 nr = re_ * br - im_ * bi;
                im_ = re_ * bi + im_ * br;
                re_ = nr;
            }
            f2 sr = br * br - bi * bi;
            bi = 2.0f * br * bi;
            br = sr;
            ee >>= 1;
        }
    };
    auto rpow = [&](int e_) {
        f2 b = rho, acc = make2(1.0f);
        int ee = e_;
        while (ee) {
            if (ee & 1) acc *= b;
            b *= b;
            ee >>= 1;
        }
        return acc;
    };

    f2 re, im;      cpow(j, re, im);
    f2 s1r, s1i;    cpow(d1, s1r, s1i);
    f2 s2r, s2i;    cpow(d2, s2r, s2i);
    f2 rstep1 = rpow(d1);
    f2 rstep2 = rpow(d2);
    f2 rho_m  = rpow(j);                 // rho^m at m = j

    f2 sum = (j == 0) ? make2(1.0f) : make2(0.0f);   // l = 0 term

    const float4* __restrict__ hp = hrec + j * NREC * 2;
    const Cons4*  __restrict__ sp = (const Cons4*)(stream + j * SMAX);

    float4 h0 = hp[0];
    float4 h1 = hp[1];

    int g = 0;
    #pragma unroll 1
    for (int k = 0; k < 4; ++k) {
        int sm = __builtin_amdgcn_readfirstlane(zcol(j, k));
        float4 h0n = hp[2 * k + 2];      // next column head (record 4 = tail)
        float4 h1n = hp[2 * k + 3];

        f2 q0 = h0.x * rho_m;                      // q at l = m
        f2 sA = q0 * h0.z;
        f2 sB = q0 * h0.w;
        f2 q1 = (h0.y * u) * (rho_m * rho);        // q at l = m+1
        sA += q1 * h1.x;
        sB += q1 * h1.y;

        int ntr = __builtin_amdgcn_readfirstlane((63 - sm + 7) >> 3);
        #pragma unroll 1
        for (int tr = 0; tr < ntr; ++tr) {
            Cons4 ca = sp[g];                      // s_load_dwordx16
            Cons4 cb = sp[g + 1];                  // s_load_dwordx16
            g += 2;
            #pragma unroll
            for (int q4 = 0; q4 < 4; ++q4) {
                float4 cc = ca.v[q4];
                f2 t4 = nrho2 * (cc.x * q0);
                f2 q  = ur * q1 + t4;
                sA += q * cc.y;
                sB += q * cc.z;
                q0 = q1; q1 = q;
            }
            #pragma unroll
            for (int q4 = 0; q4 < 4; ++q4) {
                float4 cc = cb.v[q4];
                f2 t4 = nrho2 * (cc.x * q0);
                f2 q  = ur * q1 + t4;
                sA += q * cc.y;
                sB += q * cc.z;
                q0 = q1; q1 = q;
            }
        }
        sum += re * sA + im * sB;

        if (k < 3) {                     // advance to next column start
            if (k & 1) {
                f2 nr = re * s2r - im * s2i;
                im = re * s2i + im * s2r; re = nr;
                rho_m *= rstep2;
            } else {
                f2 nr = re * s1r - im * s1i;
                im = re * s1i + im * s1r; re = nr;
                rho_m *= rstep1;
            }
        }
        h0 = h0n; h1 = h1n;
    }
    // m=64 diagonal tail: advance one step (m: 63-j -> 64 valid for j=0;
    // record 4 is zeros for j!=0 so garbage powers are inert)
    {
        f2 nr = sv * re - tv * im;
        f2 ni = sv * im + tv * re;
        re = nr; im = ni;
        rho_m *= rho;
        f2 q0 = h0.x * rho_m;            // h0 == record 4 after the loop
        sum += (re * q0) * h0.z + (im * q0) * h0.w;
    }

    part[j][e] = sum;
    __syncthreads();
    if (j == 0) {
        f2 tot = make2(0.0f);
        #pragma unroll
        for (int q = 0; q < NSUB; ++q) tot += part[q][e];
        f2 res = -(MU_F / r) * tot;
        if (base + e < B)      out[base + e]      = res.x;
        if (base + 64 + e < B) out[base + 64 + e] = res.y;
    }
}

extern "C" void kernel_launch(void* const* d_in, const int* in_sizes, int n_in,
                              void* d_out, int out_size, void* d_ws, size_t ws_size,
                              hipStream_t stream_h) {
    const float* inputs = (const float*)d_in[0];   // (B, 4)
    const float* cBar   = (const float*)d_in[1];   // (67, 67)
    const float* sBar   = (const float*)d_in[2];   // (67, 67)
    float* out = (float*)d_out;
    int B = in_sizes[0] / 4;

    float4* strm = (float4*)d_ws;                  // NSUB*SMAX = 2560 float4
    float4* hrec = strm + NSUB * SMAX;             // NSUB*NREC*2 = 160 float4

    hipLaunchKernelGGL(pines_setup, dim3(1), dim3(256), 0, stream_h,
                       cBar, sBar, strm, hrec);

    int blocks = (B + 127) / 128;
    hipLaunchKernelGGL(pines_kernel, dim3(blocks), dim3(1024), 0, stream_h,
                       (const float4*)inputs, strm, hrec, out, B);
}